// Round 1
// 408.761 us; speedup vs baseline: 1.1521x; 1.1521x over previous
//
#include <hip/hip_runtime.h>
#include <stdint.h>

#define BB 32
#define SS 8400
#define LL 80
#define DD 256
#define KK 300

// monotone map f32 -> u32, DESCENDING float order (unique per bit pattern)
__device__ __forceinline__ uint32_t f32_desc_ord(float f) {
    uint32_t u = __builtin_bit_cast(uint32_t, f);
    uint32_t asc = (u & 0x80000000u) ? ~u : (u | 0x80000000u);
    return ~asc;
}

// Kernel 1: per (b,s) row: key32 = desc-ord of max over 80 f32 labels.
// BW-bound: 86 MB read @ ~6.3 TB/s ~= 14 us floor.
__global__ __launch_bounds__(256) void k_scores(const float* __restrict__ cls,
                                                uint32_t* __restrict__ keys32) {
    int r = blockIdx.x * 256 + threadIdx.x;   // r in [0, B*S)
    const float4* row = (const float4*)(cls + (size_t)r * LL);  // 320B, 16B-aligned
    float m = -3.4e38f;
#pragma unroll
    for (int i = 0; i < 20; ++i) {
        float4 v = row[i];
        m = fmaxf(m, fmaxf(fmaxf(v.x, v.y), fmaxf(v.z, v.w)));
    }
    keys32[r] = f32_desc_ord(m);
}

// Kernel 2: one block (1024 threads) per batch.
// 4-pass radix select of the KK-th smallest 32-bit key (desc-ord => top-k scores),
// parallel 256-bin prefix scan per pass (no serial tid==0 scan),
// wave-aggregated histogram atomics (scores cluster in few digit bins),
// then collect keys <= T and rank-by-counting over (key<<32|idx) pairs.
// lax.top_k semantics: score descending, index ascending on exact ties ==
// (key asc, idx asc) lexicographic => u64 pair compare.
__global__ __launch_bounds__(1024) void k_topk(const uint32_t* __restrict__ keys32,
                                               int* __restrict__ topk) {
    __shared__ uint32_t keys[SS];              // 33,600 B
    __shared__ uint32_t hist[256];
    __shared__ uint32_t wsum[4];
    __shared__ unsigned long long sel[512];
    __shared__ uint32_t sh_prefix, sh_k, sh_cnt;

    const int b = blockIdx.x;
    const int tid = threadIdx.x;
    const int lane = tid & 63;
    const uint32_t* src = keys32 + (size_t)b * SS;

    for (int i = tid; i < SS; i += 1024) keys[i] = src[i];
    if (tid == 0) { sh_prefix = 0u; sh_k = KK; sh_cnt = 0u; }
    __syncthreads();

    for (int pos = 24; pos >= 0; pos -= 8) {
        if (tid < 256) hist[tid] = 0u;
        const uint32_t pref = sh_prefix;   // written last iter before trailing barrier
        const uint32_t krem = sh_k;
        __syncthreads();

        // histogram: uniform control flow, 9-bit ballot-match wave aggregation
        // (digit 256 = sentinel for "inactive": out of range or prefix mismatch)
#pragma unroll
        for (int r = 0; r < 9; ++r) {
            int i = tid + r * 1024;
            uint32_t d = 256u;
            if (i < SS) {
                uint32_t key = keys[i];
                if (pos == 24 || (key >> (pos + 8)) == pref)
                    d = (key >> pos) & 0xFFu;
            }
            unsigned long long mask = ~0ull;
#pragma unroll
            for (int bit = 0; bit < 9; ++bit) {
                unsigned long long bb = __ballot((d >> bit) & 1u);
                mask &= ((d >> bit) & 1u) ? bb : ~bb;
            }
            if (d < 256u && (int)__builtin_ctzll(mask) == lane)
                atomicAdd(&hist[d], (uint32_t)__popcll(mask));
        }
        __syncthreads();

        // parallel 256-bin scan: wave-level inclusive scan + 4 wave sums
        uint32_t h = 0u, cwave = 0u;
        if (tid < 256) {
            h = hist[tid];
            cwave = h;
#pragma unroll
            for (int off = 1; off < 64; off <<= 1) {
                uint32_t n = __shfl_up(cwave, (unsigned)off, 64);
                if (lane >= off) cwave += n;
            }
            if (lane == 63) wsum[tid >> 6] = cwave;
        }
        __syncthreads();   // wsum ready; also all pref/krem reads done before write below
        if (tid < 256) {
            uint32_t base = 0u;
            for (int w = 0; w < (tid >> 6); ++w) base += wsum[w];
            uint32_t cumInc = base + cwave;
            uint32_t cumExc = cumInc - h;
            if (cumExc < krem && krem <= cumInc) {   // exactly one tid
                sh_prefix = (pref << 8) | (uint32_t)tid;
                sh_k = krem - cumExc;
            }
        }
        __syncthreads();
    }

    // T = value of the KK-th smallest key. Collect all keys <= T as (key,idx) pairs.
    // #(keys < T) <= KK-1; overflow past 512 needs >212 exact duplicates of T -- not
    // reachable with continuous random scores.
    const uint32_t T = sh_prefix;
    for (int i = tid; i < SS; i += 1024) {
        uint32_t key = keys[i];
        if (key <= T) {
            uint32_t p = atomicAdd(&sh_cnt, 1u);
            if (p < 512u) sel[p] = ((unsigned long long)key << 32) | (uint32_t)i;
        }
    }
    __syncthreads();

    // rank-by-counting (pairs are unique => ranks are a permutation); keep rank < KK.
    // sel[m] reads are wave-uniform => LDS broadcast, conflict-free.
    uint32_t cnt = sh_cnt < 512u ? sh_cnt : 512u;
    if (tid < (int)cnt) {
        unsigned long long mine = sel[tid];
        uint32_t rank = 0u;
        for (uint32_t m = 0; m < cnt; ++m) rank += (sel[m] < mine) ? 1u : 0u;
        if (rank < KK) topk[b * KK + rank] = (int)(uint32_t)(mine & 0xFFFFFFFFull);
    }
}

// Kernel 3: gather rows. One block per (b,q), 64 threads. All f32.
__global__ __launch_bounds__(64) void k_gather(const float* __restrict__ coord,
                                               const float* __restrict__ cls,
                                               const float* __restrict__ mem,
                                               const int* __restrict__ topk,
                                               float* __restrict__ out) {
    const int r = blockIdx.x;          // b*KK + q
    const int b = r / KK;
    const int t = threadIdx.x;
    const int idx = topk[r];
    const size_t srow = (size_t)b * SS + (size_t)idx;

    // out layout (f32 elements): o0 refpts @0 (B*K*4) | o1 target (B*K*256) |
    //                            o2 logits (B*K*80)   | o3 bboxes (B*K*4)
    const size_t O1 = (size_t)BB * KK * 4;
    const size_t O2 = O1 + (size_t)BB * KK * DD;
    const size_t O3 = O2 + (size_t)BB * KK * LL;

    // target: 256 f32 = 64 lanes x float4
    {
        const float4* s = (const float4*)(mem + srow * DD);
        float4* d = (float4*)(out + O1 + (size_t)r * DD);
        d[t] = s[t];
    }
    // logits: 80 f32 = 20 lanes x float4
    if (t < 20) {
        const float4* s = (const float4*)(cls + srow * LL);
        float4* d = (float4*)(out + O2 + (size_t)r * LL);
        d[t] = s[t];
    }
    // coords: 4 f32 -> refpts verbatim copy + sigmoid -> bboxes
    if (t == 0) {
        float4 v = *(const float4*)(coord + srow * 4);
        *(float4*)(out + (size_t)r * 4) = v;
        float4 o;
        o.x = 1.0f / (1.0f + expf(-v.x));
        o.y = 1.0f / (1.0f + expf(-v.y));
        o.z = 1.0f / (1.0f + expf(-v.z));
        o.w = 1.0f / (1.0f + expf(-v.w));
        *(float4*)(out + O3 + (size_t)r * 4) = o;
    }
}

extern "C" void kernel_launch(void* const* d_in, const int* in_sizes, int n_in,
                              void* d_out, int out_size, void* d_ws, size_t ws_size,
                              hipStream_t stream) {
    const float* cls   = (const float*)d_in[0];  // (B,S,80) f32
    const float* coord = (const float*)d_in[1];  // (B,S,4) f32
    const float* mem   = (const float*)d_in[2];  // (B,S,256) f32
    // d_in[3] sources_last_element: unused by the reference
    float* out = (float*)d_out;

    uint32_t* keys32 = (uint32_t*)d_ws;                         // B*S u32 = 1,075,200 B
    int* topk = (int*)((char*)d_ws + (size_t)BB * SS * 4);      // B*K int

    k_scores<<<(BB * SS) / 256, 256, 0, stream>>>(cls, keys32);
    k_topk<<<BB, 1024, 0, stream>>>(keys32, topk);
    k_gather<<<BB * KK, 64, 0, stream>>>(coord, cls, mem, topk, out);
}

// Round 3
// 392.756 us; speedup vs baseline: 1.1990x; 1.0408x over previous
//
#include <hip/hip_runtime.h>
#include <stdint.h>

#define BB 32
#define SS 8400
#define LL 80
#define DD 256
#define KK 300

// Kernel 1: max over 80 labels per row -> desc-ord u32 key.
// Block-cooperative: 64 rows/block, 1280 float4 loads fully lane-coalesced
// (old version: 320B lane stride = 64 distinct lines per instruction).
// asc-ord u32 is monotone in float value, so atomicMax commutes with fmax.
__global__ __launch_bounds__(256) void k_scores(const float* __restrict__ cls,
                                                uint32_t* __restrict__ keys32) {
    __shared__ uint32_t smax[64];
    const int tid = threadIdx.x;
    const size_t rowBase = (size_t)blockIdx.x * 64;            // 64 rows per block
    const float4* src = (const float4*)(cls + rowBase * LL);   // 1280 float4s
    if (tid < 64) smax[tid] = 0u;                              // asc=0 == -NaN, never beats real data
    __syncthreads();
#pragma unroll
    for (int j = 0; j < 5; ++j) {
        int fi = j * 256 + tid;                                // 0..1279, coalesced
        float4 v = src[fi];
        float m = fmaxf(fmaxf(v.x, v.y), fmaxf(v.z, v.w));
        uint32_t u = __builtin_bit_cast(uint32_t, m);
        uint32_t asc = (u & 0x80000000u) ? ~u : (u | 0x80000000u);
        atomicMax(&smax[fi / 20], asc);                        // row = fi/20
    }
    __syncthreads();
    if (tid < 64) keys32[rowBase + tid] = ~smax[tid];          // desc-ord
}

// wave-aggregated LDS list append (one atomic per wave per iteration)
__device__ __forceinline__ void wave_append_u16(bool cond, uint16_t val, int lane,
                                                uint32_t* counter, uint16_t* list,
                                                uint32_t cap) {
    unsigned long long m = __ballot(cond);
    if (m != 0ull) {
        int leader = (int)__builtin_ctzll(m);
        uint32_t base = 0;
        if (lane == leader) base = atomicAdd(counter, (uint32_t)__popcll(m));
        base = (uint32_t)__shfl((int)base, leader, 64);
        if (cond) {
            uint32_t p = base + (uint32_t)__popcll(m & ((1ull << lane) - 1ull));
            if (p < cap) list[p] = val;
        }
    }
}

// Kernel 2: one block (1024 thr) per batch. 4x8-bit radix select on u32 keys
// with early compaction: passes 3/4 + collect run on ~300-600 surviving
// candidates instead of 8400. Histograms are 4-way replicated (stride 260,
// bank-padded) to bound same-address LDS atomic serialization.
// lax.top_k semantics: (key asc, idx asc) lexicographic == u64 pair compare.
__global__ __launch_bounds__(1024) void k_topk(const uint32_t* __restrict__ keys32,
                                               int* __restrict__ topk) {
    __shared__ uint32_t keys[SS];              // 33,600 B
    __shared__ uint16_t listA[SS];             // 16,800 B  (byte3 <= d1 candidates)
    __shared__ uint16_t listB[2048];           //  4,096 B  (16-bit prefix <= p16)
    __shared__ uint32_t hist[4 * 260];         //  4,160 B  (4 replicas, padded)
    __shared__ unsigned long long sel[512];    //  4,096 B
    __shared__ uint32_t wsum[4];
    __shared__ uint32_t sh_prefix, sh_k, sh_cnt, sh_nA, sh_nB;
    // total ~62.8 KB static LDS (< 64 KB limit)

    const int b = blockIdx.x;
    const int tid = threadIdx.x;
    const int lane = tid & 63;
    const int rep = (tid >> 7) & 3;            // 4 histogram replicas
    const uint32_t* src = keys32 + (size_t)b * SS;

    if (tid == 0) { sh_prefix = 0u; sh_k = KK; sh_cnt = 0u; sh_nA = 0u; sh_nB = 0u; }

    // --- parallel 256-bin scan + select; one thread updates sh_prefix/sh_k ---
#define SCAN_SELECT()                                                          \
    {                                                                          \
        uint32_t krem = sh_k, pref = sh_prefix;                                \
        uint32_t h = 0, cwave = 0;                                             \
        if (tid < 256) {                                                       \
            h = hist[tid] + hist[260 + tid] + hist[520 + tid] + hist[780 + tid]; \
            cwave = h;                                                         \
            _Pragma("unroll")                                                  \
            for (int off = 1; off < 64; off <<= 1) {                           \
                uint32_t nv = __shfl_up(cwave, (unsigned)off, 64);             \
                if (lane >= off) cwave += nv;                                  \
            }                                                                  \
            if (lane == 63) wsum[tid >> 6] = cwave;                            \
        }                                                                      \
        __syncthreads();  /* wsum ready; also fences krem/pref reads */        \
        if (tid < 256) {                                                       \
            uint32_t base = 0;                                                 \
            for (int w = 0; w < (tid >> 6); ++w) base += wsum[w];              \
            uint32_t cumInc = base + cwave, cumExc = cumInc - h;               \
            if (cumExc < krem && krem <= cumInc) {   /* exactly one tid */     \
                sh_prefix = (pref << 8) | (uint32_t)tid;                       \
                sh_k = krem - cumExc;                                          \
            }                                                                  \
        }                                                                      \
        __syncthreads();                                                       \
    }

#define ZERO_HIST()                                                            \
    for (int i = tid; i < 4 * 260; i += 1024) hist[i] = 0u;

    // ---- pass 1: global -> LDS stage + histogram byte 3 ----
    ZERO_HIST();
    __syncthreads();
    for (int i = tid; i < SS; i += 1024) {
        uint32_t key = src[i];
        keys[i] = key;
        atomicAdd(&hist[rep * 260 + (key >> 24)], 1u);
    }
    __syncthreads();
    SCAN_SELECT();                       // -> d1 in sh_prefix

    // ---- pass 2: histogram byte 2 among byte3==d1; compact byte3<=d1 -> listA ----
    ZERO_HIST();
    const uint32_t d1 = sh_prefix;       // stable: next write is in SCAN_SELECT below
    __syncthreads();
    for (int i = tid; i < SS; i += 1024) {
        uint32_t key = keys[i];
        uint32_t b3 = key >> 24;
        if (b3 == d1) atomicAdd(&hist[rep * 260 + ((key >> 16) & 0xFFu)], 1u);
        wave_append_u16(b3 <= d1, (uint16_t)i, lane, &sh_nA, listA, SS);
    }
    __syncthreads();
    SCAN_SELECT();                       // -> p16 in sh_prefix

    // ---- pass 3: over listA (~cumExc+n1): histogram byte 1; compact -> listB ----
    ZERO_HIST();
    const uint32_t p16 = sh_prefix;
    const int nA = (int)sh_nA;           // listA fully written (barrier above)
    __syncthreads();
    for (int j = tid; j < nA; j += 1024) {
        uint16_t idx = listA[j];
        uint32_t key = keys[idx];
        uint32_t t16 = key >> 16;
        if (t16 == p16) atomicAdd(&hist[rep * 260 + ((key >> 8) & 0xFFu)], 1u);
        wave_append_u16(t16 <= p16, idx, lane, &sh_nB, listB, 2048u);
    }
    __syncthreads();
    SCAN_SELECT();                       // -> p24 in sh_prefix

    // ---- pass 4: over listB (~300-600): histogram byte 0 ----
    ZERO_HIST();
    const uint32_t p24 = sh_prefix;
    int nB = (int)sh_nB;
    if (nB > 2048) nB = 2048;            // data-dependent bound; see listB sizing note
    __syncthreads();
    for (int j = tid; j < nB; j += 1024) {
        uint32_t key = keys[listB[j]];
        if ((key >> 8) == p24) atomicAdd(&hist[rep * 260 + (key & 0xFFu)], 1u);
    }
    __syncthreads();
    SCAN_SELECT();                       // -> full 32-bit threshold T

    // ---- collect: all keys <= T live in listB (prefix <= p24 => <= p16 etc.) ----
    const uint32_t T = sh_prefix;
    for (int j = tid; j < nB; j += 1024) {
        uint16_t idx = listB[j];
        uint32_t key = keys[idx];
        bool cond = key <= T;
        unsigned long long m = __ballot(cond);
        if (m != 0ull) {
            int leader = (int)__builtin_ctzll(m);
            uint32_t base = 0;
            if (lane == leader) base = atomicAdd(&sh_cnt, (uint32_t)__popcll(m));
            base = (uint32_t)__shfl((int)base, leader, 64);
            if (cond) {
                uint32_t p = base + (uint32_t)__popcll(m & ((1ull << lane) - 1ull));
                if (p < 512u) sel[p] = ((unsigned long long)key << 32) | idx;
            }
        }
    }
    __syncthreads();

    // rank-by-counting: pairs unique => ranks are a permutation; keep rank < KK.
    uint32_t cnt = sh_cnt < 512u ? sh_cnt : 512u;
    if (tid < (int)cnt) {
        unsigned long long mine = sel[tid];
        uint32_t rank = 0u;
        for (uint32_t m2 = 0; m2 < cnt; ++m2) rank += (sel[m2] < mine) ? 1u : 0u;
        if (rank < KK) topk[b * KK + rank] = (int)(uint32_t)(mine & 0xFFFFFFFFull);
    }
#undef SCAN_SELECT
#undef ZERO_HIST
}

// Kernel 3: gather rows. One block per (b,q), 64 threads. All f32.
__global__ __launch_bounds__(64) void k_gather(const float* __restrict__ coord,
                                               const float* __restrict__ cls,
                                               const float* __restrict__ mem,
                                               const int* __restrict__ topk,
                                               float* __restrict__ out) {
    const int r = blockIdx.x;          // b*KK + q
    const int b = r / KK;
    const int t = threadIdx.x;
    const int idx = topk[r];
    const size_t srow = (size_t)b * SS + (size_t)idx;

    // out layout (f32 elements): o0 refpts @0 (B*K*4) | o1 target (B*K*256) |
    //                            o2 logits (B*K*80)   | o3 bboxes (B*K*4)
    const size_t O1 = (size_t)BB * KK * 4;
    const size_t O2 = O1 + (size_t)BB * KK * DD;
    const size_t O3 = O2 + (size_t)BB * KK * LL;

    // target: 256 f32 = 64 lanes x float4
    {
        const float4* s = (const float4*)(mem + srow * DD);
        float4* d = (float4*)(out + O1 + (size_t)r * DD);
        d[t] = s[t];
    }
    // logits: 80 f32 = 20 lanes x float4
    if (t < 20) {
        const float4* s = (const float4*)(cls + srow * LL);
        float4* d = (float4*)(out + O2 + (size_t)r * LL);
        d[t] = s[t];
    }
    // coords: 4 f32 -> refpts verbatim copy + sigmoid -> bboxes
    if (t == 0) {
        float4 v = *(const float4*)(coord + srow * 4);
        *(float4*)(out + (size_t)r * 4) = v;
        float4 o;
        o.x = 1.0f / (1.0f + expf(-v.x));
        o.y = 1.0f / (1.0f + expf(-v.y));
        o.z = 1.0f / (1.0f + expf(-v.z));
        o.w = 1.0f / (1.0f + expf(-v.w));
        *(float4*)(out + O3 + (size_t)r * 4) = o;
    }
}

extern "C" void kernel_launch(void* const* d_in, const int* in_sizes, int n_in,
                              void* d_out, int out_size, void* d_ws, size_t ws_size,
                              hipStream_t stream) {
    const float* cls   = (const float*)d_in[0];  // (B,S,80) f32
    const float* coord = (const float*)d_in[1];  // (B,S,4) f32
    const float* mem   = (const float*)d_in[2];  // (B,S,256) f32
    // d_in[3] sources_last_element: unused by the reference
    float* out = (float*)d_out;

    uint32_t* keys32 = (uint32_t*)d_ws;                         // B*S u32 = 1,075,200 B
    int* topk = (int*)((char*)d_ws + (size_t)BB * SS * 4);      // B*K int

    k_scores<<<(BB * SS) / 64, 256, 0, stream>>>(cls, keys32);  // 4200 blocks, 64 rows each
    k_topk<<<BB, 1024, 0, stream>>>(keys32, topk);
    k_gather<<<BB * KK, 64, 0, stream>>>(coord, cls, mem, topk, out);
}

// Round 4
// 390.353 us; speedup vs baseline: 1.2064x; 1.0062x over previous
//
#include <hip/hip_runtime.h>
#include <stdint.h>

#define BB 32
#define SS 8400
#define LL 80
#define DD 256
#define KK 300

// Kernel 1: max over 80 labels per row -> desc-ord u32 key.
// Block-cooperative: 64 rows/block, fully lane-coalesced float4 loads.
// Per-float4 maxes land in a stride-21-padded LDS array (conflict-free:
// writer lanes are address-consecutive; reader lane t has bank 21t%32,
// all 32 banks covered, t vs t+32 is the free 2-way alias), then 64
// lanes reduce 20 values each. Replaces ~20-way same-address atomicMax.
__global__ __launch_bounds__(256) void k_scores(const float* __restrict__ cls,
                                                uint32_t* __restrict__ keys32) {
    __shared__ float sval[64 * 21];                            // 5376 B
    const int tid = threadIdx.x;
    const size_t rowBase = (size_t)blockIdx.x * 64;            // 64 rows per block
    const float4* src = (const float4*)(cls + rowBase * LL);   // 1280 float4s
#pragma unroll
    for (int j = 0; j < 5; ++j) {
        int fi = j * 256 + tid;                                // 0..1279, coalesced
        float4 v = src[fi];
        int r = fi / 20, c = fi - r * 20;                      // row, float4-slot
        sval[r * 21 + c] = fmaxf(fmaxf(v.x, v.y), fmaxf(v.z, v.w));
    }
    __syncthreads();
    if (tid < 64) {
        const float* row = &sval[tid * 21];
        float m = row[0];
#pragma unroll
        for (int i = 1; i < 20; ++i) m = fmaxf(m, row[i]);
        uint32_t u = __builtin_bit_cast(uint32_t, m);
        uint32_t asc = (u & 0x80000000u) ? ~u : (u | 0x80000000u);
        keys32[rowBase + tid] = ~asc;                          // desc-ord
    }
}

// Kernel 2: one block (1024 thr) per batch. Single-pass 13-bit-prefix select:
// scores (max of 80 Gaussians) cluster into one exponent byte, so byte-wise
// radix degenerates (all keys share byte3). A 13-bit prefix (sign+8exp+4mant)
// gives bin width ~0.125 at the k=300 threshold -> crossing bin ~135 keys,
// so candidates (prefix < p13: <300, plus the p13 bin) ~450 << 1024 cap.
// Histogram uses 14-bit ballot-match wave aggregation (one atomic per
// distinct bin per wave -- immune to the clustering), then a 1024-thread
// block scan of 8192 bins finds p13; collect prefix<=p13 and rank-by-count.
// lax.top_k tie semantics: (key asc, idx asc) == u64 (key<<32|idx) asc.
__global__ __launch_bounds__(1024) void k_topk(const uint32_t* __restrict__ keys32,
                                               int* __restrict__ topk) {
    __shared__ uint32_t hist[8192];            // 32,768 B
    __shared__ unsigned long long sel[1024];   //  8,192 B
    __shared__ uint32_t wtot[16];
    __shared__ uint32_t sh_p, sh_cnt;
    // ~41 KB static LDS

    const int b = blockIdx.x;
    const int tid = threadIdx.x;
    const int lane = tid & 63;
    const int wid = tid >> 6;                  // 16 waves
    const uint32_t* src = keys32 + (size_t)b * SS;

    for (int i = tid; i < 8192; i += 1024) hist[i] = 0u;
    if (tid == 0) { sh_p = 0u; sh_cnt = 0u; }
    __syncthreads();

    // ---- pass 1: 13-bit-prefix histogram, ballot-match aggregated ----
#pragma unroll
    for (int r = 0; r < 9; ++r) {
        int i = tid + r * 1024;
        uint32_t d = 16383u;                   // sentinel: out of range
        if (i < SS) d = src[i] >> 19;
        unsigned long long mask = ~0ull;
#pragma unroll
        for (int bit = 0; bit < 14; ++bit) {
            unsigned long long bb = __ballot((d >> bit) & 1u);
            mask &= ((d >> bit) & 1u) ? bb : ~bb;
        }
        if (d < 8192u && (int)__builtin_ctzll(mask) == lane)
            atomicAdd(&hist[d], (uint32_t)__popcll(mask));
    }
    __syncthreads();

    // ---- block scan over 8192 bins (8 bins/thread) -> crossing bin p13 ----
    uint32_t loc[8];
    uint32_t s = 0;
#pragma unroll
    for (int i = 0; i < 8; ++i) { loc[i] = hist[8 * tid + i]; s += loc[i]; }
    uint32_t w = s;                            // wave-inclusive scan of thread sums
#pragma unroll
    for (int off = 1; off < 64; off <<= 1) {
        uint32_t n = __shfl_up(w, (unsigned)off, 64);
        if (lane >= off) w += n;
    }
    if (lane == 63) wtot[wid] = w;
    __syncthreads();
    if (tid < 16) {                            // scan the 16 wave totals
        uint32_t v = wtot[tid];
#pragma unroll
        for (int off = 1; off < 16; off <<= 1) {
            uint32_t n = __shfl_up(v, (unsigned)off, 64);
            if (lane >= off) v += n;
        }
        wtot[tid] = v;                         // inclusive
    }
    __syncthreads();
    {
        uint32_t base = (wid > 0) ? wtot[wid - 1] : 0u;
        uint32_t cumInc = base + w;            // inclusive through this thread
        uint32_t cumExc = cumInc - s;          // exclusive before this thread
        if (cumExc < KK && KK <= cumInc) {     // exactly one thread
            uint32_t c = cumExc;
#pragma unroll
            for (int i = 0; i < 8; ++i) {
                if (KK <= c + loc[i]) { sh_p = 8u * tid + i; break; }
                c += loc[i];
            }
        }
    }
    __syncthreads();
    const uint32_t p13 = sh_p;

    // ---- collect: all keys with prefix <= p13 (contains the full top-KK) ----
    for (int i = tid; i < SS; i += 1024) {
        uint32_t key = src[i];
        bool cond = (key >> 19) <= p13;
        unsigned long long m = __ballot(cond);
        if (m != 0ull) {
            int leader = (int)__builtin_ctzll(m);
            uint32_t base2 = 0;
            if (lane == leader) base2 = atomicAdd(&sh_cnt, (uint32_t)__popcll(m));
            base2 = (uint32_t)__shfl((int)base2, leader, 64);
            if (cond) {
                uint32_t p = base2 + (uint32_t)__popcll(m & ((1ull << lane) - 1ull));
                if (p < 1024u) sel[p] = ((unsigned long long)key << 32) | (uint32_t)i;
            }
        }
    }
    __syncthreads();

    // ---- rank-by-count (pairs unique => permutation); keep rank < KK ----
    uint32_t cnt = sh_cnt < 1024u ? sh_cnt : 1024u;
    if (tid < (int)cnt) {
        unsigned long long mine = sel[tid];
        uint32_t rank = 0u;
        for (uint32_t m2 = 0; m2 < cnt; ++m2) rank += (sel[m2] < mine) ? 1u : 0u;
        if (rank < KK) topk[b * KK + rank] = (int)(uint32_t)(mine & 0xFFFFFFFFull);
    }
}

// Kernel 3: gather rows. One block per (b,q), 64 threads. All f32.
__global__ __launch_bounds__(64) void k_gather(const float* __restrict__ coord,
                                               const float* __restrict__ cls,
                                               const float* __restrict__ mem,
                                               const int* __restrict__ topk,
                                               float* __restrict__ out) {
    const int r = blockIdx.x;          // b*KK + q
    const int b = r / KK;
    const int t = threadIdx.x;
    const int idx = topk[r];
    const size_t srow = (size_t)b * SS + (size_t)idx;

    // out layout (f32 elements): o0 refpts @0 (B*K*4) | o1 target (B*K*256) |
    //                            o2 logits (B*K*80)   | o3 bboxes (B*K*4)
    const size_t O1 = (size_t)BB * KK * 4;
    const size_t O2 = O1 + (size_t)BB * KK * DD;
    const size_t O3 = O2 + (size_t)BB * KK * LL;

    // target: 256 f32 = 64 lanes x float4
    {
        const float4* s = (const float4*)(mem + srow * DD);
        float4* d = (float4*)(out + O1 + (size_t)r * DD);
        d[t] = s[t];
    }
    // logits: 80 f32 = 20 lanes x float4
    if (t < 20) {
        const float4* s = (const float4*)(cls + srow * LL);
        float4* d = (float4*)(out + O2 + (size_t)r * LL);
        d[t] = s[t];
    }
    // coords: 4 f32 -> refpts verbatim copy + sigmoid -> bboxes
    if (t == 0) {
        float4 v = *(const float4*)(coord + srow * 4);
        *(float4*)(out + (size_t)r * 4) = v;
        float4 o;
        o.x = 1.0f / (1.0f + expf(-v.x));
        o.y = 1.0f / (1.0f + expf(-v.y));
        o.z = 1.0f / (1.0f + expf(-v.z));
        o.w = 1.0f / (1.0f + expf(-v.w));
        *(float4*)(out + O3 + (size_t)r * 4) = o;
    }
}

extern "C" void kernel_launch(void* const* d_in, const int* in_sizes, int n_in,
                              void* d_out, int out_size, void* d_ws, size_t ws_size,
                              hipStream_t stream) {
    const float* cls   = (const float*)d_in[0];  // (B,S,80) f32
    const float* coord = (const float*)d_in[1];  // (B,S,4) f32
    const float* mem   = (const float*)d_in[2];  // (B,S,256) f32
    // d_in[3] sources_last_element: unused by the reference
    float* out = (float*)d_out;

    uint32_t* keys32 = (uint32_t*)d_ws;                         // B*S u32 = 1,075,200 B
    int* topk = (int*)((char*)d_ws + (size_t)BB * SS * 4);      // B*K int

    k_scores<<<(BB * SS) / 64, 256, 0, stream>>>(cls, keys32);  // 4200 blocks, 64 rows each
    k_topk<<<BB, 1024, 0, stream>>>(keys32, topk);
    k_gather<<<BB * KK, 64, 0, stream>>>(coord, cls, mem, topk, out);
}